// Round 8
// baseline (969.750 us; speedup 1.0000x reference)
//
#include <hip/hip_runtime.h>
#include <hip/hip_bf16.h>
#include <stdint.h>

// B=2, H=16, S=2048, D=64, dropout p=0.1, key = jax.random.key(42)
// JAX partitionable threefry: bits(f) = y0^y1, (y0,y1)=threefry2x32(key,(0,f))
typedef __attribute__((ext_vector_type(8))) short short8;
typedef __attribute__((ext_vector_type(4))) float f32x4;
typedef __attribute__((ext_vector_type(4))) uint32_t u32x4;
typedef __attribute__((ext_vector_type(2))) uint32_t u32x2;

#define KEEP_TH 0xE6666600u  // bits < TH  <=>  jax uniform(bits) < float32(0.9)

// 2x f32 -> packed bf16 pair in ONE op (RNE). No builtin on gfx950; inline asm.
__device__ __forceinline__ uint32_t pkbf(float lo, float hi) {
  uint32_t r;
  asm("v_cvt_pk_bf16_f32 %0, %1, %2" : "=v"(r) : "v"(lo), "v"(hi));
  return r;
}

// threefry2x32 with key (0,42), counter (0, f), x1pre = f + 42 already added.
// ks = [0, 42, 0x1BD11BF0]. Returns y0 ^ y1.
__device__ __forceinline__ uint32_t tf_bits(uint32_t x1pre) {
  uint32_t x1 = x1pre;
  uint32_t x0 = x1;                                   // round 1: x0 = 0 + x1
  x1 = __builtin_rotateleft32(x1, 13) ^ x0;
#define R(r) { x0 += x1; x1 = __builtin_rotateleft32(x1, (r)) ^ x0; }
  R(15) R(26) R(6)
  x0 += 42u;          x1 += 0x1BD11BF0u + 1u;
  R(17) R(29) R(16) R(24)
  x0 += 0x1BD11BF0u;  x1 += 2u;
  R(13) R(15) R(26) R(6)
                      x1 += 42u + 3u;
  R(17) R(29) R(16) R(24)
  x0 += 42u;          x1 += 0x1BD11BF0u + 4u;
  R(13) R(15) R(26) R(6)
  x0 += 0x1BD11BF0u;  x1 += 5u;
#undef R
  return x0 ^ x1;
}

// ---------------- DIAGNOSTIC: threefry-only workload, 3 reps ----------------
// Same per-thread cell assignment as the main kernel (512 cells/lane/rep).
// All calls kept live via accumulation + ws store (rule #17).
__global__ __launch_bounds__(256, 4)
void attn_tfonly(uint32_t* __restrict__ WsU) {
  const int tid = threadIdx.x;
  const int w = tid >> 6, l = tid & 63, e = l & 15, g = l >> 4;
  const int m = blockIdx.x & 1023;
  const int bh = (m & 7) * 4 + ((m >> 3) & 3);
  const int b = bh >> 4, h = bh & 15, qc = m >> 5;
  const int sq = qc * 64 + w * 16 + e;
  const uint32_t fb = ((uint32_t)b << 26) | ((uint32_t)h << 22) | ((uint32_t)sq << 11);
  uint32_t s0 = 0, s1 = 0, s2 = 0, s3 = 0;
  for (int rep = 0; rep < 3; ++rep) {
    for (int tile = 0; tile < 32; ++tile) {
      const int t0 = tile * 64;
#pragma unroll
      for (int Tk = 0; Tk < 4; ++Tk) {
        const uint32_t jT = fb + (uint32_t)(t0 + 16 * Tk + 4 * g + 42) + (uint32_t)rep;
        s0 += tf_bits(jT);
        s1 += tf_bits(jT + 1u);
        s2 += tf_bits(jT + 2u);
        s3 += tf_bits(jT + 3u);
      }
    }
  }
  WsU[((unsigned)blockIdx.x * 256u + (unsigned)tid) & 65535u] = (s0 ^ s1) + (s2 ^ s3);
}

// ---------------- MAIN: exact R6 kernel (best known: 281 us) ----------------
// LDS layout: flat arrays of 512 x 16B "entries" (4 u32 = 8 bf16 along K).
//  K  entry (Tk,kc,g,e) = ((Tk*2+kc)*4+g)*16+e : K[key=Tk*16+e][d=kc*32+8g..+7]
//  V  entry (dt,gk,e)   = (dt*8+gk)*16+e       : V[key=8gk..8gk+7][d=dt*16+e]
//  P  entry (w,gp,e)    = (w*8+gp)*16+e        : P[query=e][key=8gp..8gp+7]
__global__ __launch_bounds__(256, 4)
void attn_dropout_kernel(const float* __restrict__ Qg, const float* __restrict__ Kg,
                         const float* __restrict__ Vg, const float* __restrict__ invs,
                         float* __restrict__ Out) {
  __shared__ __align__(16) uint32_t KbF[512 * 4];
  __shared__ __align__(16) uint32_t VtF[512 * 4];
  __shared__ __align__(16) uint32_t PlF[512 * 4];

  const int tid = threadIdx.x;
  const int w = tid >> 6;
  const int l = tid & 63;
  const int e = l & 15;
  const int g = l >> 4;

  const int n  = blockIdx.x;                     // 0..1023
  const int bh = (n & 7) * 4 + ((n >> 3) & 3);   // 0..31
  const int b  = bh >> 4;
  const int h  = bh & 15;
  const int qc = n >> 5;                         // 0..31
  const int qbase = qc * 64;

  const float c = 1.4426950408889634f / invs[0]; // log2(e)/inv_scale, folded into Q
  const int sq = qbase + w * 16 + e;             // this lane's query row

  short8 qf[2];
#pragma unroll
  for (int kc = 0; kc < 2; ++kc) {
    const float* qp = Qg + (((b * 2048 + sq) * 16 + h) * 64 + kc * 32 + 8 * g);
    f32x4 q0 = *(const f32x4*)qp;
    f32x4 q1 = *(const f32x4*)(qp + 4);
    u32x4 u;
    u.x = pkbf(q0.x * c, q0.y * c);
    u.y = pkbf(q0.z * c, q0.w * c);
    u.z = pkbf(q1.x * c, q1.y * c);
    u.w = pkbf(q1.z * c, q1.w * c);
    qf[kc] = __builtin_bit_cast(short8, u);
  }

  f32x4 acc[4];
#pragma unroll
  for (int dt = 0; dt < 4; ++dt) acc[dt] = (f32x4){0.f, 0.f, 0.f, 0.f};
  float ls[4] = {0.f, 0.f, 0.f, 0.f};

  const uint32_t fb = ((uint32_t)b << 26) | ((uint32_t)h << 22) | ((uint32_t)sq << 11);

  const int s_e = tid & 15, s_g = (tid >> 4) & 3, s_kc = (tid >> 6) & 1, s_T = tid >> 7;
  const int v_e = tid & 15, v_gk = (tid >> 4) & 7, v_dt = tid >> 7;

  const float* kbase = Kg + (((b * 2048 + s_T * 16 + s_e) * 16 + h) * 64 + s_kc * 32 + 8 * s_g);
  const float* vbase = Vg + (((b * 2048 + 8 * v_gk) * 16 + h) * 64 + v_dt * 16 + v_e);

  f32x4 kA[2], kB[2];
  float vR[2][8];

  auto prefetch = [&](int tile) {
    const int tt = tile * 64;
#pragma unroll
    for (int r2 = 0; r2 < 2; ++r2) {
      const float* p = kbase + (tt + r2 * 32) * 1024;
      kA[r2] = *(const f32x4*)p;
      kB[r2] = *(const f32x4*)(p + 4);
      const float* pv = vbase + tt * 1024 + r2 * 32;
#pragma unroll
      for (int r = 0; r < 8; ++r) vR[r2][r] = pv[r * 1024];
    }
  };

  prefetch(0);

  for (int tile = 0; tile < 32; ++tile) {
    const int t0 = tile * 64;
    __syncthreads();

#pragma unroll
    for (int r2 = 0; r2 < 2; ++r2) {
      int Tk = s_T + 2 * r2;
      u32x4 u;
      u.x = pkbf(kA[r2].x, kA[r2].y);
      u.y = pkbf(kA[r2].z, kA[r2].w);
      u.z = pkbf(kB[r2].x, kB[r2].y);
      u.w = pkbf(kB[r2].z, kB[r2].w);
      *(u32x4*)&KbF[(((Tk * 2 + s_kc) * 4 + s_g) * 16 + s_e) * 4] = u;

      int dt = v_dt + 2 * r2;
      u32x4 uv;
      uv.x = pkbf(vR[r2][0], vR[r2][1]);
      uv.y = pkbf(vR[r2][2], vR[r2][3]);
      uv.z = pkbf(vR[r2][4], vR[r2][5]);
      uv.w = pkbf(vR[r2][6], vR[r2][7]);
      *(u32x4*)&VtF[((dt * 8 + v_gk) * 16 + v_e) * 4] = uv;
    }
    __syncthreads();

    if (tile + 1 < 32) prefetch(tile + 1);

#pragma unroll
    for (int Tk = 0; Tk < 4; ++Tk) {
      u32x4 ku0 = *(const u32x4*)&KbF[(((Tk * 2 + 0) * 4 + g) * 16 + e) * 4];
      u32x4 ku1 = *(const u32x4*)&KbF[(((Tk * 2 + 1) * 4 + g) * 16 + e) * 4];
      f32x4 sacc = (f32x4){0.f, 0.f, 0.f, 0.f};
      sacc = __builtin_amdgcn_mfma_f32_16x16x32_bf16(__builtin_bit_cast(short8, ku0), qf[0], sacc, 0, 0, 0);
      sacc = __builtin_amdgcn_mfma_f32_16x16x32_bf16(__builtin_bit_cast(short8, ku1), qf[1], sacc, 0, 0, 0);
      const uint32_t jT = fb + (uint32_t)(t0 + 16 * Tk + 4 * g + 42);
      float pm[4];
#pragma unroll
      for (int r = 0; r < 4; ++r) {
        uint32_t bits = tf_bits(jT + (uint32_t)r);
        float pv = __builtin_amdgcn_exp2f(sacc[r]);
        ls[r] += pv;                        // denominator is pre-dropout
        pm[r] = (bits < KEEP_TH) ? pv : 0.f;
      }
      int gp = 2 * Tk + (g >> 1);
      u32x2 pw;
      pw.x = pkbf(pm[0], pm[1]);
      pw.y = pkbf(pm[2], pm[3]);
      *(u32x2*)&PlF[((w * 8 + gp) * 16 + e) * 4 + 2 * (g & 1)] = pw;
    }
    asm volatile("" ::: "memory");

#pragma unroll
    for (int kk = 0; kk < 2; ++kk) {
      u32x4 pu = *(const u32x4*)&PlF[((w * 8 + g + 4 * kk) * 16 + e) * 4];
      short8 pf = __builtin_bit_cast(short8, pu);
#pragma unroll
      for (int dt = 0; dt < 4; ++dt) {
        u32x4 vu = *(const u32x4*)&VtF[((dt * 8 + g + 4 * kk) * 16 + e) * 4];
        acc[dt] = __builtin_amdgcn_mfma_f32_16x16x32_bf16(pf, __builtin_bit_cast(short8, vu), acc[dt], 0, 0, 0);
      }
    }
  }

  float L = (ls[0] + ls[1]) + (ls[2] + ls[3]);
  L += __shfl_xor(L, 16);
  L += __shfl_xor(L, 32);
  float rinv = 1.0f / (0.9f * L);
  float rr[4];
#pragma unroll
  for (int r = 0; r < 4; ++r) rr[r] = __shfl(rinv, 4 * g + r);
#pragma unroll
  for (int dt = 0; dt < 4; ++dt)
#pragma unroll
    for (int r = 0; r < 4; ++r) {
      int s = qbase + w * 16 + 4 * g + r;
      Out[(((b * 16 + h) * 2048 + s) * 64) + dt * 16 + e] = acc[dt][r] * rr[r];
    }
}

extern "C" void kernel_launch(void* const* d_in, const int* in_sizes, int n_in,
                              void* d_out, int out_size, void* d_ws, size_t ws_size,
                              hipStream_t stream) {
  const float* q  = (const float*)d_in[0];
  const float* k  = (const float*)d_in[1];
  const float* v  = (const float*)d_in[2];
  const float* sc = (const float*)d_in[3];
  float* out = (float*)d_out;
  (void)in_sizes; (void)n_in; (void)out_size;

  // Diagnostic dispatch (visible in top-5 as the slowest kernel; 3 reps of the
  // full-mask threefry workload). Main kernel's dur = round_dur - tfonly_dur.
  if (ws_size >= 262144) {
    attn_tfonly<<<dim3(1024), dim3(256), 0, stream>>>((uint32_t*)d_ws);
  }
  attn_dropout_kernel<<<dim3(1024), dim3(256), 0, stream>>>(q, k, v, sc, out);
}

// Round 9
// 280.922 us; speedup vs baseline: 3.4520x; 3.4520x over previous
//
#include <hip/hip_runtime.h>
#include <hip/hip_bf16.h>
#include <stdint.h>

// B=2, H=16, S=2048, D=64, dropout p=0.1, key = jax.random.key(42)
// JAX partitionable threefry: bits(f) = y0^y1, (y0,y1)=threefry2x32(key,(0,f))
typedef __attribute__((ext_vector_type(8))) short short8;
typedef __attribute__((ext_vector_type(4))) float f32x4;
typedef __attribute__((ext_vector_type(2))) float f32x2;
typedef __attribute__((ext_vector_type(4))) uint32_t u32x4;
typedef __attribute__((ext_vector_type(2))) uint32_t u32x2;

// 2x f32 -> packed bf16 pair in ONE op (RNE). No builtin on gfx950; inline asm.
__device__ __forceinline__ uint32_t pkbf(float lo, float hi) {
  uint32_t r;
  asm("v_cvt_pk_bf16_f32 %0, %1, %2" : "=v"(r) : "v"(lo), "v"(hi));
  return r;
}

// threefry2x32 with key (0,42), counter (0, f), x1pre = f + 42 already added.
// ks = [0, 42, 0x1BD11BF0]. K2-family constants passed in SGPRs (no 32-bit
// literal fetch in the hot loop). Returns y0 ^ y1.
__device__ __forceinline__ uint32_t tf_bits(uint32_t x1pre, uint32_t k2,
                                            uint32_t k2p1, uint32_t k2p4) {
  uint32_t x1 = x1pre;
  uint32_t x0 = x1;                                   // round 1: x0 = 0 + x1
  x1 = __builtin_rotateleft32(x1, 13) ^ x0;
#define R(r) { x0 += x1; x1 = __builtin_rotateleft32(x1, (r)) ^ x0; }
  R(15) R(26) R(6)
  x0 += 42u;   x1 += k2p1;
  R(17) R(29) R(16) R(24)
  x0 += k2;    x1 += 2u;
  R(13) R(15) R(26) R(6)
               x1 += 45u;            // ks[1] + 3  (inline const)
  R(17) R(29) R(16) R(24)
  x0 += 42u;   x1 += k2p4;
  R(13) R(15) R(26) R(6)
  x0 += k2;    x1 += 5u;
#undef R
  return x0 ^ x1;
}

// LDS layout: flat arrays of 512 x 16B "entries" (4 u32 = 8 bf16 along K).
//  K  entry (Tk,kc,g,e) = ((Tk*2+kc)*4+g)*16+e : K[key=Tk*16+e][d=kc*32+8g..+7]
//  V  entry (dt,gk,e)   = (dt*8+gk)*16+e       : V[key=8gk..8gk+7][d=dt*16+e]
//  P  entry (w,gp,e)    = (w*8+gp)*16+e        : P[query=e][key=8gp..8gp+7]
// All fragment reads/writes are 64 consecutive entries per wave -> conflict-free.
__global__ __launch_bounds__(256, 4)
void attn_dropout_kernel(const float* __restrict__ Qg, const float* __restrict__ Kg,
                         const float* __restrict__ Vg, const float* __restrict__ invs,
                         float* __restrict__ Out) {
  __shared__ __align__(16) uint32_t KbF[512 * 4];
  __shared__ __align__(16) uint32_t VtF[512 * 4];
  __shared__ __align__(16) uint32_t PlF[512 * 4];

  const int tid = threadIdx.x;
  const int w = tid >> 6;
  const int l = tid & 63;
  const int e = l & 15;
  const int g = l >> 4;

  // SGPR-pinned constants (asm source is opaque -> cannot become literals)
  uint32_t k2, k2p1, k2p4, th;
  asm("s_mov_b32 %0, 0x1BD11BF0" : "=s"(k2));
  asm("s_mov_b32 %0, 0x1BD11BF1" : "=s"(k2p1));
  asm("s_mov_b32 %0, 0x1BD11BF4" : "=s"(k2p4));
  asm("s_mov_b32 %0, 0xE6666600" : "=s"(th));  // bits < th <=> uniform < 0.9f

  const int n  = blockIdx.x;                     // 0..1023
  const int bh = (n & 7) * 4 + ((n >> 3) & 3);   // 0..31
  const int b  = bh >> 4;
  const int h  = bh & 15;
  const int qc = n >> 5;                         // 0..31
  const int qbase = qc * 64;

  const float c = 1.4426950408889634f / invs[0]; // log2(e)/inv_scale, folded into Q
  const int sq = qbase + w * 16 + e;             // this lane's query row

  short8 qf[2];
#pragma unroll
  for (int kc = 0; kc < 2; ++kc) {
    const float* qp = Qg + (((b * 2048 + sq) * 16 + h) * 64 + kc * 32 + 8 * g);
    f32x4 q0 = *(const f32x4*)qp;
    f32x4 q1 = *(const f32x4*)(qp + 4);
    u32x4 u;
    u.x = pkbf(q0.x * c, q0.y * c);
    u.y = pkbf(q0.z * c, q0.w * c);
    u.z = pkbf(q1.x * c, q1.y * c);
    u.w = pkbf(q1.z * c, q1.w * c);
    qf[kc] = __builtin_bit_cast(short8, u);
  }

  f32x4 acc[4];
#pragma unroll
  for (int dt = 0; dt < 4; ++dt) acc[dt] = (f32x4){0.f, 0.f, 0.f, 0.f};
  f32x2 ls01 = (f32x2){0.f, 0.f}, ls23 = (f32x2){0.f, 0.f};  // v_pk_add_f32 pairs

  const uint32_t fb = ((uint32_t)b << 26) | ((uint32_t)h << 22) | ((uint32_t)sq << 11);
  const uint32_t jlane = fb + 4u * (uint32_t)g + 42u;  // + (t0+16Tk+r) scalar addend

  const int s_e = tid & 15, s_g = (tid >> 4) & 3, s_kc = (tid >> 6) & 1, s_T = tid >> 7;
  const int v_e = tid & 15, v_gk = (tid >> 4) & 7, v_dt = tid >> 7;

  const float* kbase = Kg + (((b * 2048 + s_T * 16 + s_e) * 16 + h) * 64 + s_kc * 32 + 8 * s_g);
  const float* vbase = Vg + (((b * 2048 + 8 * v_gk) * 16 + h) * 64 + v_dt * 16 + v_e);

  f32x4 kA[2], kB[2];
  float vR[2][8];

  auto prefetch = [&](int tile) {
    const int tt = tile * 64;
#pragma unroll
    for (int r2 = 0; r2 < 2; ++r2) {
      const float* p = kbase + (tt + r2 * 32) * 1024;
      kA[r2] = *(const f32x4*)p;
      kB[r2] = *(const f32x4*)(p + 4);
      const float* pv = vbase + tt * 1024 + r2 * 32;
#pragma unroll
      for (int r = 0; r < 8; ++r) vR[r2][r] = pv[r * 1024];
    }
  };

  prefetch(0);

  for (int tile = 0; tile < 32; ++tile) {
    const int t0 = tile * 64;
    __syncthreads();

#pragma unroll
    for (int r2 = 0; r2 < 2; ++r2) {
      int Tk = s_T + 2 * r2;
      u32x4 u;
      u.x = pkbf(kA[r2].x, kA[r2].y);
      u.y = pkbf(kA[r2].z, kA[r2].w);
      u.z = pkbf(kB[r2].x, kB[r2].y);
      u.w = pkbf(kB[r2].z, kB[r2].w);
      *(u32x4*)&KbF[(((Tk * 2 + s_kc) * 4 + s_g) * 16 + s_e) * 4] = u;

      int dt = v_dt + 2 * r2;
      u32x4 uv;
      uv.x = pkbf(vR[r2][0], vR[r2][1]);
      uv.y = pkbf(vR[r2][2], vR[r2][3]);
      uv.z = pkbf(vR[r2][4], vR[r2][5]);
      uv.w = pkbf(vR[r2][6], vR[r2][7]);
      *(u32x4*)&VtF[((dt * 8 + v_gk) * 16 + v_e) * 4] = uv;
    }
    __syncthreads();

    if (tile + 1 < 32) prefetch(tile + 1);

#pragma unroll
    for (int Tk = 0; Tk < 4; ++Tk) {
      u32x4 ku0 = *(const u32x4*)&KbF[(((Tk * 2 + 0) * 4 + g) * 16 + e) * 4];
      u32x4 ku1 = *(const u32x4*)&KbF[(((Tk * 2 + 1) * 4 + g) * 16 + e) * 4];
      f32x4 sacc = (f32x4){0.f, 0.f, 0.f, 0.f};
      sacc = __builtin_amdgcn_mfma_f32_16x16x32_bf16(__builtin_bit_cast(short8, ku0), qf[0], sacc, 0, 0, 0);
      sacc = __builtin_amdgcn_mfma_f32_16x16x32_bf16(__builtin_bit_cast(short8, ku1), qf[1], sacc, 0, 0, 0);
      const uint32_t base = (uint32_t)(t0 + 16 * Tk);   // wave-uniform scalar addend
      float pm[4], pv[4];
#pragma unroll
      for (int r = 0; r < 4; ++r) {
        uint32_t bits = tf_bits(jlane + base + (uint32_t)r, k2, k2p1, k2p4);
        pv[r] = __builtin_amdgcn_exp2f(sacc[r]);
        pm[r] = (bits < th) ? pv[r] : 0.f;   // denominator is pre-dropout
      }
      ls01 += (f32x2){pv[0], pv[1]};
      ls23 += (f32x2){pv[2], pv[3]};
      int gp = 2 * Tk + (g >> 1);
      u32x2 pw;
      pw.x = pkbf(pm[0], pm[1]);
      pw.y = pkbf(pm[2], pm[3]);
      *(u32x2*)&PlF[((w * 8 + gp) * 16 + e) * 4 + 2 * (g & 1)] = pw;
    }
    asm volatile("" ::: "memory");  // same-wave DS ops are in-order; pin compiler order

#pragma unroll
    for (int kk = 0; kk < 2; ++kk) {
      u32x4 pu = *(const u32x4*)&PlF[((w * 8 + g + 4 * kk) * 16 + e) * 4];
      short8 pf = __builtin_bit_cast(short8, pu);
#pragma unroll
      for (int dt = 0; dt < 4; ++dt) {
        u32x4 vu = *(const u32x4*)&VtF[((dt * 8 + g + 4 * kk) * 16 + e) * 4];
        acc[dt] = __builtin_amdgcn_mfma_f32_16x16x32_bf16(pf, __builtin_bit_cast(short8, vu), acc[dt], 0, 0, 0);
      }
    }
  }

  f32x2 lsv = ls01 + ls23;
  float L = lsv.x + lsv.y;
  L += __shfl_xor(L, 16);
  L += __shfl_xor(L, 32);               // full row-sum for query e in all g-lanes
  float rinv = 1.0f / (0.9f * L);
  float rr[4];
#pragma unroll
  for (int r = 0; r < 4; ++r) rr[r] = __shfl(rinv, 4 * g + r);
#pragma unroll
  for (int dt = 0; dt < 4; ++dt)
#pragma unroll
    for (int r = 0; r < 4; ++r) {
      int s = qbase + w * 16 + 4 * g + r;      // D row = (lane>>4)*4 + reg
      Out[(((b * 16 + h) * 2048 + s) * 64) + dt * 16 + e] = acc[dt][r] * rr[r];
    }
}

extern "C" void kernel_launch(void* const* d_in, const int* in_sizes, int n_in,
                              void* d_out, int out_size, void* d_ws, size_t ws_size,
                              hipStream_t stream) {
  const float* q  = (const float*)d_in[0];
  const float* k  = (const float*)d_in[1];
  const float* v  = (const float*)d_in[2];
  const float* sc = (const float*)d_in[3];
  float* out = (float*)d_out;
  (void)d_ws; (void)ws_size; (void)in_sizes; (void)n_in; (void)out_size;
  attn_dropout_kernel<<<dim3(1024), dim3(256), 0, stream>>>(q, k, v, sc, out);
}